// Round 11
// baseline (222.767 us; speedup 1.0000x reference)
//
#include <hip/hip_runtime.h>
#include <math.h>

#define NB   16
#define NN   307
#define Q4   77           // m-tiles of 4 (MPAD=308)
#define MPAD 308
#define KCH  3
#define IND  66           // INPUT_DIM + HIDDEN
#define KI   198          // KCH * IND
#define HID  64
#define HG   128          // 2 * HIDDEN
#define NG   77           // n-groups of 4 per b

typedef float f32x4 __attribute__((ext_vector_type(4)));

// ws layout (floats)
#define OFF_GP  0
#define SZ_GP   (KCH * NN * MPAD)         // 283,668
#define OFF_X1  (OFF_GP + SZ_GP)
#define SZ_X    (NB * Q4 * IND * 4)       // 325,248  x tiled: [b][q][i][e], m = 4q+e
#define OFF_X2  (OFF_X1 + SZ_X)
#define OFF_Z   (OFF_X2 + SZ_X)
#define SZ_X2I  (NB * Q4 * 2 * 4)         // x2 xt-row init elements (i<2 only)

// K0: padded G copy [k][n][m(308)]; x1 = combined tiled [b][q][i][e];
//     x2: only i<2 rows (xt) written — i>=2 rows written by gate each call,
//     m-pad elements multiply G_p zeros (exact 0 contribution).
__global__ void prep_kernel(const float* __restrict__ G,
                            const float* __restrict__ xt,
                            const float* __restrict__ h,
                            float* __restrict__ G_p,
                            float* __restrict__ x1,
                            float* __restrict__ x2) {
    int idx = blockIdx.x * blockDim.x + threadIdx.x;
    if (idx < SZ_GP) {
        int mp = idx % MPAD;
        int kn = idx / MPAD;
        G_p[idx] = (mp < NN) ? G[kn * NN + mp] : 0.f;
    } else if (idx < SZ_GP + SZ_X) {
        int j = idx - SZ_GP;
        int e = j & 3;
        int t = j >> 2;
        int i = t % IND;
        int q = (t / IND) % Q4;
        int b = t / (IND * Q4);
        int m = q * 4 + e;
        float v = 0.f;
        if (m < NN)
            v = (i < 2) ? xt[(b * NN + m) * 2 + i]
                        : h[(b * NN + m) * HID + (i - 2)];
        x1[j] = v;
    } else if (idx < SZ_GP + SZ_X + SZ_X2I) {
        int j = idx - SZ_GP - SZ_X;
        int e  = j & 3;
        int t  = j >> 2;
        int i  = t & 1;
        int t2 = t >> 1;
        int q  = t2 % Q4;
        int b  = t2 / Q4;
        int m  = q * 4 + e;
        float v = (m < NN) ? xt[(b * NN + m) * 2 + i] : 0.f;
        x2[(((size_t)b * Q4 + q) * IND + i) * 4 + e] = v;
    }
}

// ---- shared phase-1: wave computes sup rows for 2 panels (na, nb) into s ----
__device__ __forceinline__ void phase1_wave(const f32x4* __restrict__ G4,
                                            const f32x4* __restrict__ X4,
                                            int b, int na, int nb,
                                            float* __restrict__ sA,
                                            float* __restrict__ sB,
                                            int lane) {
    const int nac = (na < NN) ? na : (NN - 1);
    const int nbc = (nb < NN) ? nb : (NN - 1);
    const f32x4* xp  = X4 + (size_t)b * (Q4 * IND) + lane;   // i = lane
    const f32x4* gA0 = G4 + ((size_t)0 * NN + nac) * Q4;
    const f32x4* gA1 = G4 + ((size_t)1 * NN + nac) * Q4;
    const f32x4* gA2 = G4 + ((size_t)2 * NN + nac) * Q4;
    const f32x4* gB0 = G4 + ((size_t)0 * NN + nbc) * Q4;
    const f32x4* gB1 = G4 + ((size_t)1 * NN + nbc) * Q4;
    const f32x4* gB2 = G4 + ((size_t)2 * NN + nbc) * Q4;
    f32x4 aA0 = {0.f,0.f,0.f,0.f}, aA1 = aA0, aA2 = aA0;
    f32x4 aB0 = aA0, aB1 = aA0, aB2 = aA0;
    #pragma unroll 7
    for (int q = 0; q < Q4; ++q) {
        f32x4 xv = xp[(size_t)q * IND];       // coalesced, shared across both n
        aA0 += xv * gA0[q];  aA1 += xv * gA1[q];  aA2 += xv * gA2[q];
        aB0 += xv * gB0[q];  aB1 += xv * gB1[q];  aB2 += xv * gB2[q];
    }
    sA[0 * IND + lane] = aA0.x + aA0.y + aA0.z + aA0.w;
    sA[1 * IND + lane] = aA1.x + aA1.y + aA1.z + aA1.w;
    sA[2 * IND + lane] = aA2.x + aA2.y + aA2.z + aA2.w;
    sB[0 * IND + lane] = aB0.x + aB0.y + aB0.z + aB0.w;
    sB[1 * IND + lane] = aB1.x + aB1.y + aB1.z + aB1.w;
    sB[2 * IND + lane] = aB2.x + aB2.y + aB2.z + aB2.w;
    // tail i = 64,65 for both panels: 4 items x 16-lane q-split
    const int j  = lane >> 4;          // 0..3
    const int sl = lane & 15;
    const int ns = j >> 1;             // 0: panel A, 1: panel B
    const int it = 64 + (j & 1);
    const int nt = ns ? nbc : nac;
    f32x4 t0 = {0.f,0.f,0.f,0.f}, t1 = t0, t2 = t0;
    for (int q = sl; q < Q4; q += 16) {
        f32x4 xv = X4[(size_t)b * (Q4 * IND) + (size_t)q * IND + it];
        t0 += xv * G4[((size_t)0 * NN + nt) * Q4 + q];
        t1 += xv * G4[((size_t)1 * NN + nt) * Q4 + q];
        t2 += xv * G4[((size_t)2 * NN + nt) * Q4 + q];
    }
    float h0 = t0.x + t0.y + t0.z + t0.w;
    float h1 = t1.x + t1.y + t1.z + t1.w;
    float h2 = t2.x + t2.y + t2.z + t2.w;
    #pragma unroll
    for (int m = 1; m < 16; m <<= 1) {
        h0 += __shfl_xor(h0, m);
        h1 += __shfl_xor(h1, m);
        h2 += __shfl_xor(h2, m);
    }
    if (sl == 0) {
        float* sp = ns ? sB : sA;
        sp[0 * IND + it] = h0;
        sp[1 * IND + it] = h1;
        sp[2 * IND + it] = h2;
    }
}

// K1: fused gcn1 + gate. Wave-autonomous: 2 panels/wave, no __syncthreads.
__global__ __launch_bounds__(128) void gate_fused(const float* __restrict__ G_p,
                                                  const float* __restrict__ xT,
                                                  const float* __restrict__ W,
                                                  const float* __restrict__ bias,
                                                  const float* __restrict__ h,
                                                  float* __restrict__ z_out,
                                                  float* __restrict__ xT2) {
    __shared__ float s[4][KI];
    const int blk  = blockIdx.x;
    const int b    = blk / NG;
    const int n0   = (blk % NG) * 4;
    const int wave = threadIdx.x >> 6;
    const int lane = threadIdx.x & 63;
    const int na   = n0 + wave * 2;
    const int nb   = na + 1;
    phase1_wave((const f32x4*)G_p, (const f32x4*)xT, b, na, nb,
                s[wave * 2], s[wave * 2 + 1], lane);
    // ---- phase 2: stream both W panels with the full wave ----
    const int c = lane & 31;          // col-quad (128 cols)
    const int r = lane >> 5;          // row parity
    #pragma unroll
    for (int ps = 0; ps < 2; ++ps) {
        const int n   = na + ps;
        const int bnc = b * NN + ((n < NN) ? n : (NN - 1));
        const f32x4* Wp = (const f32x4*)W + (size_t)bnc * KI * (HG / 4) + c;
        const float* sp = s[wave * 2 + ps];
        f32x4 acc = {0.f,0.f,0.f,0.f};
        #pragma unroll 16
        for (int i = r; i < KI; i += 2) {
            f32x4 w = __builtin_nontemporal_load(Wp + (size_t)i * (HG / 4));
            acc += w * sp[i];
        }
        acc.x += __shfl_xor(acc.x, 32);
        acc.y += __shfl_xor(acc.y, 32);
        acc.z += __shfl_xor(acc.z, 32);
        acc.w += __shfl_xor(acc.w, 32);
        if (lane < 32 && n < NN) {
            const int bn = b * NN + n;
            f32x4 bv = ((const f32x4*)bias)[(size_t)bn * (HG / 4) + c];
            f32x4 a  = acc + bv;
            float g0 = 1.0f / (1.0f + expf(-a.x));
            float g1 = 1.0f / (1.0f + expf(-a.y));
            float g2 = 1.0f / (1.0f + expf(-a.z));
            float g3 = 1.0f / (1.0f + expf(-a.w));
            if (c < 16) {                       // z cols 4c..4c+3
                f32x4 zv = {g0, g1, g2, g3};
                ((f32x4*)z_out)[(size_t)bn * (HID / 4) + c] = zv;
            } else {                            // r-gate -> cand at m=n
                int hh0 = (c - 16) * 4;
                size_t base = (((size_t)b * Q4 + (n >> 2)) * IND) * 4 + (n & 3);
                xT2[base + (size_t)(2 + hh0 + 0) * 4] = g0 * h[bn * HID + hh0 + 0];
                xT2[base + (size_t)(2 + hh0 + 1) * 4] = g1 * h[bn * HID + hh0 + 1];
                xT2[base + (size_t)(2 + hh0 + 2) * 4] = g2 * h[bn * HID + hh0 + 2];
                xT2[base + (size_t)(2 + hh0 + 3) * 4] = g3 * h[bn * HID + hh0 + 3];
            }
        }
    }
}

// K2: fused gcn2 + update. Same wave-autonomous structure.
__global__ __launch_bounds__(128) void update_fused(const float* __restrict__ G_p,
                                                    const float* __restrict__ xT2,
                                                    const float* __restrict__ W,
                                                    const float* __restrict__ bias,
                                                    const float* __restrict__ z,
                                                    const float* __restrict__ h,
                                                    float* __restrict__ out) {
    __shared__ float s[4][KI];
    const int blk  = blockIdx.x;
    const int b    = blk / NG;
    const int n0   = (blk % NG) * 4;
    const int wave = threadIdx.x >> 6;
    const int lane = threadIdx.x & 63;
    const int na   = n0 + wave * 2;
    const int nb   = na + 1;
    phase1_wave((const f32x4*)G_p, (const f32x4*)xT2, b, na, nb,
                s[wave * 2], s[wave * 2 + 1], lane);
    // ---- phase 2 ----
    const int c = lane & 15;          // col-quad (64 cols)
    const int r = lane >> 4;          // row mod 4
    #pragma unroll
    for (int ps = 0; ps < 2; ++ps) {
        const int n   = na + ps;
        const int bnc = b * NN + ((n < NN) ? n : (NN - 1));
        const f32x4* Wp = (const f32x4*)W + (size_t)bnc * KI * (HID / 4) + c;
        const float* sp = s[wave * 2 + ps];
        f32x4 acc = {0.f,0.f,0.f,0.f};
        #pragma unroll 16
        for (int i = r; i < KI; i += 4) {
            f32x4 w = __builtin_nontemporal_load(Wp + (size_t)i * (HID / 4));
            acc += w * sp[i];
        }
        acc.x += __shfl_xor(acc.x, 16);
        acc.y += __shfl_xor(acc.y, 16);
        acc.z += __shfl_xor(acc.z, 16);
        acc.w += __shfl_xor(acc.w, 16);
        acc.x += __shfl_xor(acc.x, 32);
        acc.y += __shfl_xor(acc.y, 32);
        acc.z += __shfl_xor(acc.z, 32);
        acc.w += __shfl_xor(acc.w, 32);
        if (lane < 16 && n < NN) {
            const int bn = b * NN + n;
            f32x4 bv = ((const f32x4*)bias)[(size_t)bn * (HID / 4) + c];
            f32x4 a  = acc + bv;
            f32x4 zz = ((const f32x4*)z)[(size_t)bn * (HID / 4) + c];
            f32x4 hv = ((const f32x4*)h)[(size_t)bn * (HID / 4) + c];
            f32x4 o;
            o.x = zz.x * tanhf(a.x) + (1.f - zz.x) * hv.x;
            o.y = zz.y * tanhf(a.y) + (1.f - zz.y) * hv.y;
            o.z = zz.z * tanhf(a.z) + (1.f - zz.z) * hv.z;
            o.w = zz.w * tanhf(a.w) + (1.f - zz.w) * hv.w;
            ((f32x4*)out)[(size_t)bn * (HID / 4) + c] = o;
        }
    }
}

extern "C" void kernel_launch(void* const* d_in, const int* in_sizes, int n_in,
                              void* d_out, int out_size, void* d_ws, size_t ws_size,
                              hipStream_t stream) {
    const float* G  = (const float*)d_in[0];
    const float* xt = (const float*)d_in[1];
    const float* h  = (const float*)d_in[2];
    const float* Wg = (const float*)d_in[3];
    const float* bg = (const float*)d_in[4];
    const float* Wu = (const float*)d_in[5];
    const float* bu = (const float*)d_in[6];
    float* out = (float*)d_out;

    float* ws   = (float*)d_ws;
    float* G_p  = ws + OFF_GP;
    float* x1   = ws + OFF_X1;
    float* x2   = ws + OFF_X2;
    float* z    = ws + OFF_Z;

    const int totPrep = SZ_GP + SZ_X + SZ_X2I;
    prep_kernel<<<(totPrep + 255) / 256, 256, 0, stream>>>(G, xt, h, G_p, x1, x2);

    gate_fused<<<NB * NG, 128, 0, stream>>>(G_p, x1, Wg, bg, h, z, x2);

    update_fused<<<NB * NG, 128, 0, stream>>>(G_p, x2, Wu, bu, z, h, out);
}

// Round 12
// 211.259 us; speedup vs baseline: 1.0545x; 1.0545x over previous
//
#include <hip/hip_runtime.h>
#include <math.h>

#define NB   16
#define NN   307
#define MPAD 308          // padded m for G rows
#define Q4   77           // MPAD/4: m-tiles of 4
#define KCH  3
#define IND  66           // INPUT_DIM + HIDDEN
#define KI   198          // KCH * IND
#define HID  64
#define HG   128          // 2 * HIDDEN

typedef float f32x4 __attribute__((ext_vector_type(4)));

// ws layout (floats)
#define OFF_GP  0
#define SZ_GP   (KCH * NN * MPAD)         // 283,668
#define OFF_X1  (OFF_GP + SZ_GP)
#define SZ_X    (NB * Q4 * IND * 4)       // 325,248  x tiled: [b][q][i][e], m = 4q+e
#define OFF_X2  (OFF_X1 + SZ_X)
#define OFF_Z   (OFF_X2 + SZ_X)
#define SZ_X2I  (NB * Q4 * 2 * 4)         // x2 xt-row init elements (i<2 only)

// K0: padded G copy [k][n][m(308)]; x1 = combined tiled [b][q][i][e];
//     x2: only i<2 rows (xt) written — i>=2 rows written by gate each call,
//     m-pad elements multiply G_p zeros (exact 0 contribution).
__global__ void prep_kernel(const float* __restrict__ G,
                            const float* __restrict__ xt,
                            const float* __restrict__ h,
                            float* __restrict__ G_p,
                            float* __restrict__ x1,
                            float* __restrict__ x2) {
    int idx = blockIdx.x * blockDim.x + threadIdx.x;
    if (idx < SZ_GP) {
        int mp = idx % MPAD;
        int kn = idx / MPAD;
        G_p[idx] = (mp < NN) ? G[kn * NN + mp] : 0.f;
    } else if (idx < SZ_GP + SZ_X) {
        int j = idx - SZ_GP;
        int e = j & 3;
        int t = j >> 2;
        int i = t % IND;
        int q = (t / IND) % Q4;
        int b = t / (IND * Q4);
        int m = q * 4 + e;
        float v = 0.f;
        if (m < NN)
            v = (i < 2) ? xt[(b * NN + m) * 2 + i]
                        : h[(b * NN + m) * HID + (i - 2)];
        x1[j] = v;
    } else if (idx < SZ_GP + SZ_X + SZ_X2I) {
        int j = idx - SZ_GP - SZ_X;
        int e  = j & 3;
        int t  = j >> 2;
        int i  = t & 1;
        int t2 = t >> 1;
        int q  = t2 % Q4;
        int b  = t2 / Q4;
        int m  = q * 4 + e;
        float v = (m < NN) ? xt[(b * NN + m) * 2 + i] : 0.f;
        x2[(((size_t)b * Q4 + q) * IND + i) * 4 + e] = v;
    }
}

// ---- shared phase-1: both waves active via q-parity split; result in s ----
__device__ __forceinline__ void phase1_block(const f32x4* __restrict__ G4,
                                             const f32x4* __restrict__ X4,
                                             int b, int n, int tid,
                                             float part[2][KCH][IND],
                                             float* __restrict__ s) {
    const int wave = tid >> 6;
    const int lane = tid & 63;
    const f32x4* xp = X4 + (size_t)b * (Q4 * IND) + lane;   // i = lane (0..63)
    const f32x4* g0 = G4 + ((size_t)0 * NN + n) * Q4;
    const f32x4* g1 = G4 + ((size_t)1 * NN + n) * Q4;
    const f32x4* g2 = G4 + ((size_t)2 * NN + n) * Q4;
    f32x4 a0 = {0.f,0.f,0.f,0.f}, a1 = a0, a2 = a0;
    #pragma unroll 8
    for (int q = wave; q < Q4; q += 2) {     // wave0: even q, wave1: odd q
        f32x4 xv = xp[(size_t)q * IND];      // 64 lanes x 16B contiguous
        a0 += xv * g0[q];                     // wave-uniform broadcasts
        a1 += xv * g1[q];
        a2 += xv * g2[q];
    }
    part[wave][0][lane] = a0.x + a0.y + a0.z + a0.w;
    part[wave][1][lane] = a1.x + a1.y + a1.z + a1.w;
    part[wave][2][lane] = a2.x + a2.y + a2.z + a2.w;
    // tail i = 64,65: wave0, 32-lane q-strided + shfl reduce; wave1 zeroes slots
    if (wave == 0) {
        const int it = 64 + (lane >> 5);
        const int sl = lane & 31;
        f32x4 t0 = {0.f,0.f,0.f,0.f}, t1 = t0, t2 = t0;
        for (int q = sl; q < Q4; q += 32) {
            f32x4 xv = X4[(size_t)b * (Q4 * IND) + (size_t)q * IND + it];
            t0 += xv * g0[q];
            t1 += xv * g1[q];
            t2 += xv * g2[q];
        }
        float h0 = t0.x + t0.y + t0.z + t0.w;
        float h1 = t1.x + t1.y + t1.z + t1.w;
        float h2 = t2.x + t2.y + t2.z + t2.w;
        #pragma unroll
        for (int m = 1; m < 32; m <<= 1) {
            h0 += __shfl_xor(h0, m);
            h1 += __shfl_xor(h1, m);
            h2 += __shfl_xor(h2, m);
        }
        if (sl == 0) {
            part[0][0][it] = h0;
            part[0][1][it] = h1;
            part[0][2][it] = h2;
        }
    } else if (lane < 6) {
        part[1][lane >> 1][64 + (lane & 1)] = 0.f;
    }
    __syncthreads();
    for (int t = tid; t < KI; t += 128) {
        int k = t / IND, i = t % IND;
        s[t] = part[0][k][i] + part[1][k][i];
    }
    __syncthreads();
}

// K1: fused gcn1 + gate.
__global__ __launch_bounds__(128) void gate_fused(const float* __restrict__ G_p,
                                                  const float* __restrict__ xT,
                                                  const float* __restrict__ W,
                                                  const float* __restrict__ bias,
                                                  const float* __restrict__ h,
                                                  float* __restrict__ z_out,
                                                  float* __restrict__ xT2) {
    __shared__ float part[2][KCH][IND];
    __shared__ float s[KI];
    __shared__ float red[4][HG];
    const int bn  = blockIdx.x;
    const int b   = bn / NN;
    const int n   = bn % NN;
    const int tid = threadIdx.x;
    phase1_block((const f32x4*)G_p, (const f32x4*)xT, b, n, tid, part, s);
    // ---- phase 2: W stream (R7-identical) ----
    const int r  = tid >> 5;
    const int c4 = (tid & 31) * 4;
    const f32x4* Wp = (const f32x4*)(W + (size_t)bn * KI * HG + c4);
    float4 acc = make_float4(0.f, 0.f, 0.f, 0.f);
    #pragma unroll 8
    for (int i = r; i < KI; i += 4) {
        f32x4 w = __builtin_nontemporal_load(Wp + (size_t)i * (HG / 4));
        float sv = s[i];
        acc.x += sv * w.x; acc.y += sv * w.y;
        acc.z += sv * w.z; acc.w += sv * w.w;
    }
    red[r][c4 + 0] = acc.x; red[r][c4 + 1] = acc.y;
    red[r][c4 + 2] = acc.z; red[r][c4 + 3] = acc.w;
    __syncthreads();
    float a = bias[bn * HG + tid] + red[0][tid] + red[1][tid] + red[2][tid] + red[3][tid];
    float g = 1.0f / (1.0f + expf(-a));
    if (tid < HID) {
        z_out[bn * HID + tid] = g;                    // z
    } else {
        int hh = tid - HID;                           // r gate -> candidate elem at m=n
        int q = n >> 2, e = n & 3;
        xT2[(((size_t)b * Q4 + q) * IND + 2 + hh) * 4 + e] = g * h[bn * HID + hh];
    }
}

// K2: fused gcn2 + update.
__global__ __launch_bounds__(128) void update_fused(const float* __restrict__ G_p,
                                                    const float* __restrict__ xT2,
                                                    const float* __restrict__ W,
                                                    const float* __restrict__ bias,
                                                    const float* __restrict__ z,
                                                    const float* __restrict__ h,
                                                    float* __restrict__ out) {
    __shared__ float part[2][KCH][IND];
    __shared__ float s[KI];
    __shared__ float red[8][HID];
    const int bn  = blockIdx.x;
    const int b   = bn / NN;
    const int n   = bn % NN;
    const int tid = threadIdx.x;
    phase1_block((const f32x4*)G_p, (const f32x4*)xT2, b, n, tid, part, s);
    // ---- phase 2 (R7-identical) ----
    const int r  = tid >> 4;
    const int c4 = (tid & 15) * 4;
    const f32x4* Wp = (const f32x4*)(W + (size_t)bn * KI * HID + c4);
    float4 acc = make_float4(0.f, 0.f, 0.f, 0.f);
    #pragma unroll 8
    for (int i = r; i < KI; i += 8) {
        f32x4 w = __builtin_nontemporal_load(Wp + (size_t)i * (HID / 4));
        float sv = s[i];
        acc.x += sv * w.x; acc.y += sv * w.y;
        acc.z += sv * w.z; acc.w += sv * w.w;
    }
    red[r][c4 + 0] = acc.x; red[r][c4 + 1] = acc.y;
    red[r][c4 + 2] = acc.z; red[r][c4 + 3] = acc.w;
    __syncthreads();
    if (tid < HID) {
        float a = bias[bn * HID + tid];
        #pragma unroll
        for (int rr = 0; rr < 8; ++rr) a += red[rr][tid];
        float nn = tanhf(a);
        float zz = z[bn * HID + tid];
        float hv = h[bn * HID + tid];
        out[bn * HID + tid] = zz * nn + (1.f - zz) * hv;
    }
}

extern "C" void kernel_launch(void* const* d_in, const int* in_sizes, int n_in,
                              void* d_out, int out_size, void* d_ws, size_t ws_size,
                              hipStream_t stream) {
    const float* G  = (const float*)d_in[0];
    const float* xt = (const float*)d_in[1];
    const float* h  = (const float*)d_in[2];
    const float* Wg = (const float*)d_in[3];
    const float* bg = (const float*)d_in[4];
    const float* Wu = (const float*)d_in[5];
    const float* bu = (const float*)d_in[6];
    float* out = (float*)d_out;

    float* ws   = (float*)d_ws;
    float* G_p  = ws + OFF_GP;
    float* x1   = ws + OFF_X1;
    float* x2   = ws + OFF_X2;
    float* z    = ws + OFF_Z;

    const int totPrep = SZ_GP + SZ_X + SZ_X2I;
    prep_kernel<<<(totPrep + 255) / 256, 256, 0, stream>>>(G, xt, h, G_p, x1, x2);

    gate_fused<<<NB * NN, 128, 0, stream>>>(G_p, x1, Wg, bg, h, z, x2);

    update_fused<<<NB * NN, 128, 0, stream>>>(G_p, x2, Wu, bu, z, h, out);
}